// Round 1
// 154.844 us; speedup vs baseline: 1.0102x; 1.0102x over previous
//
#include <hip/hip_runtime.h>

// SSIM loss: pred/target [16,3,512,512] fp32, 11x11 gaussian (sigma=1.5),
// zero-padded SAME depthwise conv, output scalar 1 - mean(ssim_map).
//
// v7: packed-fp32 math. The v6 algebraic reduction (u=p+t, v=p-t ->
// four conv chains (cu,cv,cu2,cv2)) is kept, but all float2 lane-math in
// both conv passes now uses VOP3P v_pk_fma_f32 / v_pk_mul_f32 via inline
// asm (hipcc does not auto-form packed fp32). Plus a squares-precompute:
// sq[i] = uv[i]^2 once per pixel, so each tap is exactly
//   amu = pk_fma(uv, w, amu); asq = pk_fma(sq, w, asq)
// = 2 instructions/tap (was 6 in phase B, 4 in phase C).
// One float4 LDS plane (39.1 KB) -> 4 blocks/CU. Phase B hoists both
// unconditional items' global loads before compute.

#define IMG 512
#define NCHAN 48
#define TW 32
#define TH 64
#define HR (TH + 10)   // 74 hsum rows per tile
#define PST 33         // padded plane row stride (float4s)

typedef float v2f __attribute__((ext_vector_type(2)));

constexpr double RW1 = 0.8007374029168082;
constexpr double RW2 = 0.4111122905071876;
constexpr double RW3 = 0.1353352832366127;
constexpr double RW4 = 0.0285655007845504;
constexpr double RW5 = 0.0038659201394728;
constexpr double RSUM = 1.0 + 2.0 * (RW1 + RW2 + RW3 + RW4 + RW5);
constexpr float GW[11] = {
    (float)(RW5 / RSUM), (float)(RW4 / RSUM), (float)(RW3 / RSUM),
    (float)(RW2 / RSUM), (float)(RW1 / RSUM), (float)(1.0 / RSUM),
    (float)(RW1 / RSUM), (float)(RW2 / RSUM), (float)(RW3 / RSUM),
    (float)(RW4 / RSUM), (float)(RW5 / RSUM)};

// ---- VOP3P packed fp32 (gfx90a+; hipcc never auto-emits these)
__device__ __forceinline__ v2f pk_fma(v2f a, v2f b, v2f c) {
  v2f d;
  asm("v_pk_fma_f32 %0, %1, %2, %3" : "=v"(d) : "v"(a), "v"(b), "v"(c));
  return d;
}
__device__ __forceinline__ v2f pk_mul(v2f a, v2f b) {
  v2f d;
  asm("v_pk_mul_f32 %0, %1, %2" : "=v"(d) : "v"(a), "v"(b));
  return d;
}

// ---- Phase B building blocks: item j in [0, HR*8) = 4 hsum outputs.
template <bool CHECKED>
__device__ __forceinline__ void hload(const float* __restrict__ P,
                                      const float* __restrict__ T, int r0t,
                                      int c0, int j, float4* vp, float4* vt) {
  const int g = j & 7;
  const int h = j >> 3;
  const int gy = r0t - 5 + h;
  const int gx0 = c0 + g * 4 - 8;  // aligned 20-float window (mult of 4)
  if (CHECKED) {
    const bool rowok = (gy >= 0) && (gy < IMG);
    const float* __restrict__ Prow = P + (size_t)gy * IMG;
    const float* __restrict__ Trow = T + (size_t)gy * IMG;
#pragma unroll
    for (int q = 0; q < 5; ++q) {
      const int gx = gx0 + q * 4;
      vp[q] = make_float4(0.f, 0.f, 0.f, 0.f);
      vt[q] = vp[q];
      // gx is a multiple of 4 and IMG%4==0: float4 is all-in or all-out.
      if (rowok && gx >= 0 && gx < IMG) {
        vp[q] = *(const float4*)(Prow + gx);
        vt[q] = *(const float4*)(Trow + gx);
      }
    }
  } else {
    const float* __restrict__ Prow = P + (size_t)gy * IMG + gx0;
    const float* __restrict__ Trow = T + (size_t)gy * IMG + gx0;
#pragma unroll
    for (int q = 0; q < 5; ++q) {
      vp[q] = *(const float4*)(Prow + q * 4);
      vt[q] = *(const float4*)(Trow + q * 4);
    }
  }
}

__device__ __forceinline__ void hcompute(int j, const float4* vp,
                                         const float4* vt,
                                         float4 (*hs)[PST]) {
  const int g = j & 7;
  const int h = j >> 3;
  // (u, v) = (p+t, p-t) per pixel; only window indices 3..16 feed outputs
  // (dead lanes are DCE'd by the compiler).
  v2f uv[20], sq[20];
#pragma unroll
  for (int q = 0; q < 5; ++q) {
    const float4 p4 = vp[q], t4 = vt[q];
    uv[q * 4 + 0] = (v2f){p4.x + t4.x, p4.x - t4.x};
    uv[q * 4 + 1] = (v2f){p4.y + t4.y, p4.y - t4.y};
    uv[q * 4 + 2] = (v2f){p4.z + t4.z, p4.z - t4.z};
    uv[q * 4 + 3] = (v2f){p4.w + t4.w, p4.w - t4.w};
  }
#pragma unroll
  for (int i = 3; i <= 16; ++i) sq[i] = pk_mul(uv[i], uv[i]);
#pragma unroll
  for (int o = 0; o < 4; ++o) {
    v2f amu = (v2f){0.f, 0.f};  // (cu, cv)
    v2f asq = (v2f){0.f, 0.f};  // (cu2, cv2)
#pragma unroll
    for (int k = 0; k < 11; ++k) {
      const v2f w = (v2f){GW[k], GW[k]};
      amu = pk_fma(uv[3 + o + k], w, amu);
      asq = pk_fma(sq[3 + o + k], w, asq);
    }
    hs[h][g * 4 + o] = make_float4(amu.x, amu.y, asq.x, asq.y);
  }
}

template <bool CHECKED>
__device__ __forceinline__ void phase_b(const float* __restrict__ P,
                                        const float* __restrict__ T, int r0t,
                                        int c0, int tid, float4 (*hs)[PST]) {
  // HR*8 = 592 items: tid and tid+256 unconditional (loads hoisted so both
  // items' 20 b128 loads are in flight together), tid+512 for tid<80.
  float4 ap[5], at[5], bp[5], bt[5];
  hload<CHECKED>(P, T, r0t, c0, tid, ap, at);
  hload<CHECKED>(P, T, r0t, c0, tid + 256, bp, bt);
  hcompute(tid, ap, at, hs);
  hcompute(tid + 256, bp, bt, hs);
  if (tid < HR * 8 - 512) {
    hload<CHECKED>(P, T, r0t, c0, tid + 512, ap, at);
    hcompute(tid + 512, ap, at, hs);
  }
}

__global__ __launch_bounds__(256, 4) void ssim_main(
    const float* __restrict__ pred, const float* __restrict__ tgt,
    double* __restrict__ ws) {
  __shared__ float4 hs[HR][PST];  // (cu, cv, cu2, cv2)
  __shared__ float wsum[4];

  const int tid = threadIdx.x;
  const int c0 = blockIdx.x * TW;
  const int r0t = blockIdx.y * TH;
  const int nc = blockIdx.z;
  const size_t base = (size_t)nc * IMG * IMG;
  const float* __restrict__ P = pred + base;
  const float* __restrict__ T = tgt + base;

  const bool interior =
      (c0 != 0) && (c0 != IMG - TW) && (r0t != 0) && (r0t != IMG - TH);
  if (interior)
    phase_b<false>(P, T, r0t, c0, tid, hs);
  else
    phase_b<true>(P, T, r0t, c0, tid, hs);
  __syncthreads();

  // ---- Phase C: vertical windowed sums, row-streaming, 8 outputs/thread
  float lsum = 0.f;
  {
    const int x = tid & (TW - 1);
    const int r0 = (tid >> 5) * 8;  // 8 strips * 8 rows = 64
    v2f amu[8], asq[8];
#pragma unroll
    for (int o = 0; o < 8; ++o) {
      amu[o] = (v2f){0.f, 0.f};
      asq[o] = (v2f){0.f, 0.f};
    }
#pragma unroll
    for (int j = 0; j < 18; ++j) {
      const float4 h4 = hs[r0 + j][x];
      const v2f hmu = (v2f){h4.x, h4.y};
      const v2f hsq = (v2f){h4.z, h4.w};
#pragma unroll
      for (int o = 0; o < 8; ++o) {
        const int k = j - o;
        if (k >= 0 && k < 11) {
          const v2f w = (v2f){GW[k], GW[k]};
          amu[o] = pk_fma(hmu, w, amu[o]);
          asq[o] = pk_fma(hsq, w, asq[o]);
        }
      }
    }
#pragma unroll
    for (int o = 0; o < 8; ++o) {
      const v2f m2 = pk_mul(amu[o], amu[o]);   // (cu^2, cv^2)
      const float cusq = m2.x, cvsq = m2.y;
      const float cu2 = asq[o].x, cv2 = asq[o].y;
      const float mu12 = 0.25f * (cusq - cvsq);       // mu1*mu2
      const float musq = 0.5f * (cusq + cvsq);        // mu1^2+mu2^2
      const float s12 = 0.25f * (cu2 - cv2);          // conv(p*t)
      const float ssq = 0.5f * (cu2 + cv2);           // s11+s22
      const float num = (2.f * mu12 + 1e-4f) * (2.f * (s12 - mu12) + 9e-4f);
      const float den = (musq + 1e-4f) * (ssq - musq + 9e-4f);
      lsum += num * __builtin_amdgcn_rcpf(den);
    }
  }

  // ---- Block reduce, one f64 atomic per block into per-channel bucket
#pragma unroll
  for (int off = 32; off > 0; off >>= 1) lsum += __shfl_down(lsum, off, 64);
  if ((tid & 63) == 0) wsum[tid >> 6] = lsum;
  __syncthreads();
  if (tid == 0) {
    const float bsum = wsum[0] + wsum[1] + wsum[2] + wsum[3];
    unsafeAtomicAdd(&ws[nc], (double)bsum);
  }
}

__global__ void ssim_fin(const double* __restrict__ ws,
                         float* __restrict__ out) {
  const int l = threadIdx.x;
  double v = (l < NCHAN) ? ws[l] : 0.0;
#pragma unroll
  for (int off = 32; off > 0; off >>= 1) v += __shfl_down(v, off, 64);
  if (l == 0) out[0] = (float)(1.0 - v / (double)(IMG * IMG * NCHAN));
}

extern "C" void kernel_launch(void* const* d_in, const int* in_sizes, int n_in,
                              void* d_out, int out_size, void* d_ws,
                              size_t ws_size, hipStream_t stream) {
  const float* pred = (const float*)d_in[0];
  const float* tgt = (const float*)d_in[1];
  double* ws = (double*)d_ws;

  hipMemsetAsync(d_ws, 0, NCHAN * sizeof(double), stream);
  dim3 grid(IMG / TW, IMG / TH, NCHAN);
  ssim_main<<<grid, 256, 0, stream>>>(pred, tgt, ws);
  ssim_fin<<<1, 64, 0, stream>>>(ws, (float*)d_out);
}